// Round 5
// baseline (395.812 us; speedup 1.0000x reference)
//
#include <hip/hip_runtime.h>

// ---------------------------------------------------------------------------
// RetnetBlock fp16-MFMA implementation.
// R11: attn pipeline repair — R10 post-mortem found vmcnt pollution: STAGE
//      issued BEFORE the 16 scalar decay loads, so vmcnt(2) kept the youngest
//      (decay) ops in flight and drained STAGE(s+2) => synchronous staging at
//      1 block/CU (63us). Fix: R8 geometry (64 Q-rows x 2 batches, 256 thr,
//      grid 512, 4 KV bufs + Ss = 72.7 KB -> 2 blocks/CU) with per-step order
//      DLOAD -> sched_barrier(0) -> STAGE(s+2) -> STEP -> vmcnt(4)+s_barrier:
//      vmcnt(4) provably leaves exactly STAGE(s+2)'s 4 ops in flight. Decay
//      loads drain at their issue-step barrier (~600cy later, covered).
//      G4/G6 128x128 + XCD y-swizzle + direct f32 partial stores from R9.
// ---------------------------------------------------------------------------

typedef _Float16 f16;
typedef _Float16 f16x8 __attribute__((ext_vector_type(8)));
typedef float floatx4 __attribute__((ext_vector_type(4)));

#define EP_BIAS_F16      0
#define EP_DECAY_F16     1
#define EP_BIAS_GELU_F16 2
#define EP_PARTIAL_F32   3

template <bool F32> struct out_sel { typedef f16 T; };
template <> struct out_sel<true>   { typedef float T; };

__device__ __forceinline__ void gload_lds16(const void* g, void* s) {
    __builtin_amdgcn_global_load_lds(
        (const __attribute__((address_space(1))) unsigned int*)g,
        (__attribute__((address_space(3))) unsigned int*)s, 16, 0, 0);
}

// erf via Abramowitz-Stegun 7.1.26, |abs err| <= 1.5e-7
__device__ __forceinline__ float erf_fast(float x) {
    const float ax = fabsf(x);
    const float t  = __builtin_amdgcn_rcpf(1.f + 0.3275911f * ax);
    const float p  = t * (0.254829592f + t * (-0.284496736f + t * (1.421413741f +
                     t * (-1.453152027f + t * 1.061405429f))));
    const float r  = 1.f - p * __expf(-ax * ax);
    return copysignf(r, x);
}

// ---------------------------------------------------------------------------
// Fused attention: block = 64 Q-rows x one h x TWO batches; 256 thr = 4
// waves, wave w owns Q rows [w*16, w*16+16) x all 64 kv of the tile.
// 32 steps of (tile 0..15) x (batch 0,1); step s consumes buf[s&3], staged
// at step s-2. Per step: DLOAD(next decay) | sched_barrier | STAGE(s+2) |
// STEP(s) | s_waitcnt vmcnt(4) + s_barrier  (stage(s+2)'s 4 ops stay in
// flight across the barrier; everything older drains). S exchange via
// per-wave private LDS (in-order DS, no barrier).
// ---------------------------------------------------------------------------
__global__ __launch_bounds__(256, 2) void attn_fused(
    const f16* __restrict__ p, const f16* __restrict__ vT,
    const float* __restrict__ decay, f16* __restrict__ gated)
{
    const int y  = blockIdx.y;          // bp*16 + h
    const int bp = y >> 4, h = y & 15;
    const int m0 = blockIdx.x * 64;

    __shared__ __align__(16) f16 Kb[4][64 * 64];   // 32 KB, swizzled
    __shared__ __align__(16) f16 Vb[4][64 * 64];   // 32 KB, swizzled
    __shared__ __align__(16) f16 Ss[4][16 * 68];   // 8.7 KB, per-wave, padded

    const int t    = threadIdx.x;
    const int lane = t & 63;
    const int w    = t >> 6;            // 0..3
    const int quad = lane >> 4;
    const int fr   = lane & 15;
    const int wq0  = w * 16;            // wave's Q-row base within block

    const int b0 = bp * 2, b1 = b0 + 1;
    const f16*   Qg0 = p + (size_t)(b0 * 1024 + m0) * 4096 + h * 64;
    const f16*   Qg1 = p + (size_t)(b1 * 1024 + m0) * 4096 + h * 64;
    const f16*   Kg0 = p + (size_t)(b0 * 1024) * 4096 + 1024 + h * 64;
    const f16*   Kg1 = p + (size_t)(b1 * 1024) * 4096 + 1024 + h * 64;
    const f16*   Vg0 = vT + (size_t)(b0 * 16 + h) * 65536;   // [64][1024]
    const f16*   Vg1 = vT + (size_t)(b1 * 16 + h) * 65536;
    const f16*   XOg0 = p + (size_t)(b0 * 1024 + m0) * 4096 + 3072 + h * 64;
    const f16*   XOg1 = p + (size_t)(b1 * 1024 + m0) * 4096 + 3072 + h * 64;
    const float* Dg  = decay + (size_t)h * 1048576 + (size_t)m0 * 1024;

    // Q fragments straight to registers: row wq0+fr, k-chunk kc*4+quad.
    f16x8 q00, q01, q10, q11;
    {
        const size_t qrow = (size_t)(wq0 + fr) * 4096;
        q00 = *(const f16x8*)(Qg0 + qrow + (0 * 4 + quad) * 8);
        q01 = *(const f16x8*)(Qg0 + qrow + (1 * 4 + quad) * 8);
        q10 = *(const f16x8*)(Qg1 + qrow + (0 * 4 + quad) * 8);
        q11 = *(const f16x8*)(Qg1 + qrow + (1 * 4 + quad) * 8);
    }

    floatx4 oa0[4] = {}, oa1[4] = {};   // O accumulators, d-tiles tn=0..3
    float dA[16], dB[16];               // decay ping-pong (static indexing)

    // thread's decay base: row (m0+wq0+quad*4), col fr
    const float* Dt = Dg + (size_t)(wq0 + quad * 4) * 1024 + fr;

#define DLOAD(dst, jj) { _Pragma("unroll") \
    for (int tn = 0; tn < 4; ++tn) { _Pragma("unroll") \
      for (int r = 0; r < 4; ++r) \
        dst[tn * 4 + r] = Dt[(size_t)r * 1024 + (jj) + tn * 16]; } \
    __builtin_amdgcn_sched_barrier(0); }

// stage one (batch, tile) pair of K,V into buffer pb; 4 gload_lds/thread.
// XOR-swizzled: LDS chunk (r, sc) holds global chunk (r, sc^(r&7)).
#define STAGE(Kgp, Vgp, jj, pb) { _Pragma("unroll") \
    for (int i_ = 0; i_ < 2; ++i_) { \
      const int ci = t + i_ * 256; \
      const int r_ = ci >> 3; \
      const int c_ = ((ci & 7) ^ (r_ & 7)) * 8; \
      gload_lds16((Kgp) + (size_t)((jj) + r_) * 4096 + c_, &Kb[pb][ci * 8]); \
      gload_lds16((Vgp) + (size_t)r_ * 1024 + (jj) + c_, &Vb[pb][ci * 8]); \
    } }

// counted-vmcnt barrier: stage(s+2)'s 4 loads may stay in flight.
#define VMBAR(N) { asm volatile("s_waitcnt vmcnt(" #N ")" ::: "memory"); \
    __builtin_amdgcn_s_barrier(); __builtin_amdgcn_sched_barrier(0); }

// one step: S = Q K^T (8 MFMA) -> xdecay -> wave-private Ss -> O += S V (8 MFMA)
#define STEP(qa, qb, oa, dreg, pb) { \
    floatx4 sa[4] = {}; \
    _Pragma("unroll") \
    for (int kc = 0; kc < 2; ++kc) { \
      const int cc = kc * 4 + quad; \
      f16x8 bf[4]; \
      _Pragma("unroll") \
      for (int tn = 0; tn < 4; ++tn) { \
        const int kv = tn * 16 + fr; \
        bf[tn] = *(const f16x8*)&Kb[pb][(kv * 8 + (cc ^ (kv & 7))) * 8]; \
      } \
      _Pragma("unroll") \
      for (int tn = 0; tn < 4; ++tn) \
        sa[tn] = __builtin_amdgcn_mfma_f32_16x16x32_f16(kc ? (qb) : (qa), bf[tn], sa[tn], 0, 0, 0); \
    } \
    _Pragma("unroll") \
    for (int tn = 0; tn < 4; ++tn) { _Pragma("unroll") \
      for (int r = 0; r < 4; ++r) \
        Ss[w][(quad * 4 + r) * 68 + tn * 16 + fr] = (f16)(sa[tn][r] * dreg[tn * 4 + r]); } \
    _Pragma("unroll") \
    for (int kc = 0; kc < 2; ++kc) { \
      const int cc = kc * 4 + quad; \
      const f16x8 af = *(const f16x8*)&Ss[w][fr * 68 + cc * 8]; \
      f16x8 bf[4]; \
      _Pragma("unroll") \
      for (int tn = 0; tn < 4; ++tn) { \
        const int d = tn * 16 + fr; \
        bf[tn] = *(const f16x8*)&Vb[pb][(d * 8 + (cc ^ (d & 7))) * 8]; \
      } \
      _Pragma("unroll") \
      for (int tn = 0; tn < 4; ++tn) \
        oa[tn] = __builtin_amdgcn_mfma_f32_16x16x32_f16(af, bf[tn], oa[tn], 0, 0, 0); \
    } }

// epilogue: gate with silu(xo), stage via wave-private Ss, coalesced flush
#define EPILOG(oa, XOgp, bq) { \
    _Pragma("unroll") \
    for (int tn = 0; tn < 4; ++tn) { _Pragma("unroll") \
      for (int r = 0; r < 4; ++r) { \
        const int qrow = wq0 + quad * 4 + r; \
        const int d = tn * 16 + fr; \
        float g = (float)XOgp[(size_t)qrow * 4096 + d]; \
        g = g * __builtin_amdgcn_rcpf(1.f + __expf(-g)); \
        Ss[w][(quad * 4 + r) * 68 + tn * 16 + fr] = (f16)(oa[tn][r] * g); \
      } } \
    f16* Og = gated + (size_t)((bq) * 1024 + m0 + wq0) * 1024 + h * 64; \
    _Pragma("unroll") \
    for (int i = 0; i < 2; ++i) { \
      const int jj = lane + i * 64; \
      const int rr = jj >> 3; \
      const int cc = jj & 7; \
      const uint2 lo = *(const uint2*)&Ss[w][rr * 68 + cc * 8]; \
      const uint2 hi = *(const uint2*)&Ss[w][rr * 68 + cc * 8 + 4]; \
      uint4 val = make_uint4(lo.x, lo.y, hi.x, hi.y); \
      *(uint4*)(Og + (size_t)rr * 1024 + cc * 8) = val; \
    } }

    // prologue: DLOAD(dA) first (must drain here), then stages for steps 0,1.
    // vmcnt(4) leaves exactly stage(1)'s 4 ops in flight; drains Q, dA, stage(0).
    DLOAD(dA, 0);
    STAGE(Kg0, Vg0, 0, 0);              // step0 (t0,b0) -> buf0
    STAGE(Kg1, Vg1, 0, 1);              // step1 (t0,b1) -> buf1
    VMBAR(4);

    for (int i = 0; i < 7; ++i) {
        const int j1 = i * 128 + 64;    // tile 2i+1 base
        const int j2 = i * 128 + 128;   // tile 2i+2 base
        // s=4i: consume buf0 (t2i,b0,dA) | dload dB(t2i+1) | stage s+2 -> buf2
        DLOAD(dB, j1);
        STAGE(Kg0, Vg0, j1, 2);
        STEP(q00, q01, oa0, dA, 0);
        VMBAR(4);
        // s=4i+1: consume buf1 (t2i,b1,dA) | stage s+2 -> buf3
        STAGE(Kg1, Vg1, j1, 3);
        STEP(q10, q11, oa1, dA, 1);
        VMBAR(4);
        // s=4i+2: consume buf2 (t2i+1,b0,dB) | dload dA(t2i+2) | stage -> buf0
        DLOAD(dA, j2);
        STAGE(Kg0, Vg0, j2, 0);
        STEP(q00, q01, oa0, dB, 2);
        VMBAR(4);
        // s=4i+3: consume buf3 (t2i+1,b1,dB) | stage s+2 -> buf1
        STAGE(Kg1, Vg1, j2, 1);
        STEP(q10, q11, oa1, dB, 3);
        VMBAR(4);
    }
    // tail: steps 28..31 (tile 14 via dA from buf0/1, tile 15 via dB buf2/3)
    {
        // step 28: consume buf0 (t14,b0,dA) | dload dB(t15) | stage 30 -> buf2
        DLOAD(dB, 960);
        STAGE(Kg0, Vg0, 960, 2);
        STEP(q00, q01, oa0, dA, 0);
        VMBAR(4);
        // step 29: consume buf1 (t14,b1,dA) | stage 31 -> buf3
        STAGE(Kg1, Vg1, 960, 3);
        STEP(q10, q11, oa1, dA, 1);
        VMBAR(4);
        // step 30: consume buf2 (t15,b0,dB); nothing staged after -> vmcnt(0)
        STEP(q00, q01, oa0, dB, 2);
        VMBAR(0);
        // step 31: consume buf3 (t15,b1,dB); no barrier needed after
        STEP(q10, q11, oa1, dB, 3);
    }

    EPILOG(oa0, XOg0, b0);
    EPILOG(oa1, XOg1, b1);

#undef DLOAD
#undef STAGE
#undef VMBAR
#undef STEP
#undef EPILOG
}

// C[m,n] = sum_k A[m,k] * B[n,k]  ("BT" form). 256 thr = 4 waves, 2x2 grid.
// blockIdx.z packs ((zo*inner + zi)*nsplit + ks); split ks covers K-range
// [ks*Kc,(ks+1)*Kc), partial written at cOff + ks*sCk (EP_PARTIAL_F32,
// direct f32 stores, no LDS staging).
// XSWZ: XCD y-chunk swizzle — requires (gridDim.x*gridDim.y) % 8 == 0;
// remaps so each XCD owns a contiguous band of y-slabs (A L2-resident).
// K (and Kc) must be multiples of 64.
template <int BM, int BN, int WM, int WN, int EP, int XSWZ>
__global__ __launch_bounds__(256, 4) void gemm_bt(
    const f16* __restrict__ A, const f16* __restrict__ B, void* __restrict__ Cv,
    int M, int N, int K, int lda, int ldb, int ldc,
    long long sAo, long long sAi, long long sBo, long long sBi,
    long long sCo, long long sCi, int inner,
    int nsplit, int Kc, long long sCk,
    const float* __restrict__ bias,
    const void* __restrict__ aux, long long sXo, long long sXi, int ldaux)
{
    constexpr bool OUT_F32 = (EP == EP_PARTIAL_F32);
    typedef typename out_sel<OUT_F32>::T OutT;
    constexpr int ESIZE       = OUT_F32 ? 4 : 2;
    constexpr int CSTRIDE     = BN + 4;                  // stage row stride, elems
    constexpr int TILE_BYTES  = (BM + BN) * 64 * 2;      // BK=64 f16 tiles
    constexpr int STAGE_BYTES = OUT_F32 ? 0 : BM * CSTRIDE * ESIZE;
    constexpr int SMEM_BYTES  = TILE_BYTES > STAGE_BYTES ? TILE_BYTES : STAGE_BYTES;

    __shared__ __align__(16) char smem[SMEM_BYTES];
    f16*  As = (f16*)smem;
    f16*  Bs = (f16*)(smem + BM * 128);
    OutT* Cs = (OutT*)smem;

    int z = blockIdx.z;
    const int ks = z % nsplit; z /= nsplit;
    const int zo = z / inner, zi = z % inner;
    A += zo * sAo + zi * sAi;
    B += zo * sBo + zi * sBi;
    const long long cOff = (long long)zo * sCo + (long long)zi * sCi + (long long)ks * sCk;
    const long long xOff = (long long)zo * sXo + (long long)zi * sXi;

    int bx = blockIdx.x, by = blockIdx.y;
    if constexpr (XSWZ) {
        // hw XCD = (bx + gx*by + gx*gy*bz) % 8; with gx = 8 this is bx.
        // Remap so XCD c covers y' in [c*gy/8, (c+1)*gy/8) for all x'.
        const int gx  = gridDim.x;
        const int nb  = gx * gridDim.y;          // must be % 8 == 0
        const int lin = bx + gx * by;
        const int nlin = (lin & 7) * (nb >> 3) + (lin >> 3);
        bx = nlin % gx;
        by = nlin / gx;
    }
    const int m0 = by * BM;
    const int n0 = bx * BN;

    const int t    = threadIdx.x;
    const int lane = t & 63;
    const int w    = t >> 6;
    const int wm   = (w >> 1) * (WM * 16);
    const int wn   = (w & 1) * (WN * 16);
    const int fr   = lane & 15;          // A/B row within 16-tile
    const int quad = lane >> 4;          // 0..3, k-offset quad*8

    constexpr int ACH = BM / 32;         // 16B chunks per thread for A tile
    constexpr int BCH = BN / 32;

    floatx4 acc[WM][WN] = {};

    const int kbeg = ks * Kc, kend = kbeg + Kc;
    for (int kk = kbeg; kk < kend; kk += 64) {
        // async global->LDS, 16B/lane. LDS layout XOR-swizzled: LDS chunk
        // (r, sc) holds global chunk (r, sc ^ (r&7)).
#pragma unroll
        for (int i = 0; i < ACH; ++i) {
            const int ci = t + i * 256;
            const int r  = ci >> 3;
            const int c  = ((ci & 7) ^ (r & 7)) * 8;
            gload_lds16(A + (size_t)(m0 + r) * lda + kk + c, &As[ci * 8]);
        }
#pragma unroll
        for (int i = 0; i < BCH; ++i) {
            const int ci = t + i * 256;
            const int r  = ci >> 3;
            const int c  = ((ci & 7) ^ (r & 7)) * 8;
            gload_lds16(B + (size_t)(n0 + r) * ldb + kk + c, &Bs[ci * 8]);
        }
        __syncthreads();

#pragma unroll
        for (int kh = 0; kh < 2; ++kh) {
            const int cc = kh * 4 + quad;             // 16B chunk within row
            f16x8 af[WM], bf[WN];
#pragma unroll
            for (int tm = 0; tm < WM; ++tm) {
                const int r = wm + tm * 16 + fr;
                af[tm] = *(const f16x8*)&As[(r * 8 + (cc ^ (r & 7))) * 8];
            }
#pragma unroll
            for (int tn = 0; tn < WN; ++tn) {
                const int r = wn + tn * 16 + fr;
                bf[tn] = *(const f16x8*)&Bs[(r * 8 + (cc ^ (r & 7))) * 8];
            }
#pragma unroll
            for (int tm = 0; tm < WM; ++tm)
#pragma unroll
                for (int tn = 0; tn < WN; ++tn)
                    acc[tm][tn] = __builtin_amdgcn_mfma_f32_16x16x32_f16(af[tm], bf[tn], acc[tm][tn], 0, 0, 0);
        }
        __syncthreads();
    }

    // ---- epilogue: C/D layout col=lane&15, row=(lane>>4)*4+reg [m89] ----
    const int er = quad * 4;
    const int ec = lane & 15;
    if constexpr (OUT_F32) {
        // direct f32 stores: per instr, wave writes 4 x 64B aligned segments
        float* Pg = (float*)Cv + cOff;
#pragma unroll
        for (int tm = 0; tm < WM; ++tm)
#pragma unroll
            for (int tn = 0; tn < WN; ++tn)
#pragma unroll
                for (int r = 0; r < 4; ++r) {
                    const int grow = m0 + wm + tm * 16 + er + r;
                    const int gcol = n0 + wn + tn * 16 + ec;
                    Pg[(size_t)grow * ldc + gcol] = acc[tm][tn][r];
                }
        return;
    }

#pragma unroll
    for (int tm = 0; tm < WM; ++tm) {
#pragma unroll
        for (int tn = 0; tn < WN; ++tn) {
#pragma unroll
            for (int r = 0; r < 4; ++r) {
                const int lrow = wm + tm * 16 + er + r;       // 0..BM-1
                const int col  = wn + tn * 16 + ec;           // 0..BN-1
                const int grow = m0 + lrow;
                const int gcol = n0 + col;
                const float v = acc[tm][tn][r];
                float val;
                if constexpr (EP == EP_BIAS_F16) {
                    val = v + bias[gcol];
                } else if constexpr (EP == EP_DECAY_F16) {
                    const float* dk = (const float*)aux + xOff;
                    val = v * dk[(size_t)grow * ldaux + gcol];
                } else if constexpr (EP == EP_BIAS_GELU_F16) {
                    const float u = v + bias[gcol];
                    val = 0.5f * u * (1.f + erf_fast(u * 0.70710678118f));
                } else {
                    val = v;
                }
                Cs[lrow * CSTRIDE + col] = (OutT)val;
            }
        }
    }
    __syncthreads();

    constexpr int PER_ROW = BN * ESIZE / 16;          // 16B chunks per row
    constexpr int NCHUNK  = (BM * PER_ROW) / 256;     // chunks per thread
#pragma unroll
    for (int i = 0; i < NCHUNK; ++i) {
        const int j  = t + i * 256;
        const int rr = j / PER_ROW;
        const int cc = j - rr * PER_ROW;
        const char* src = smem + (size_t)rr * (CSTRIDE * ESIZE) + (size_t)cc * 16;
        const uint2 lo = *(const uint2*)src;          // stride 264B: 8B-aligned
        const uint2 hi = *(const uint2*)(src + 8);
        uint4 val = make_uint4(lo.x, lo.y, hi.x, hi.y);
        char* dst = (char*)Cv +
            (size_t)(cOff + (long long)(m0 + rr) * ldc + n0) * ESIZE +
            (size_t)cc * 16;
        *(uint4*)dst = val;
    }
}

// out[4096,1024] = P0 + P1 + bias[col] + res   (all f32, float4 vectorized)
__global__ __launch_bounds__(256) void reduce2_bias_res(
    const float4* __restrict__ P, const float* __restrict__ bias,
    const float4* __restrict__ res, float4* __restrict__ out)
{
    const int i = blockIdx.x * 256 + threadIdx.x;   // 1,048,576 groups
    const int col4 = i & 255;
    const float4 a = P[i];
    const float4 b = P[i + 1048576];
    const float4 r = res[i];
    const float4 bi = ((const float4*)bias)[col4];
    float4 o;
    o.x = a.x + b.x + r.x + bi.x;
    o.y = a.y + b.y + r.y + bi.y;
    o.z = a.z + b.z + r.z + bi.z;
    o.w = a.w + b.w + r.w + bi.w;
    out[i] = o;
}

// LayerNorm over D=1024, one block (256 thr) per row, fp16 output.
__global__ __launch_bounds__(256) void ln_to_f16(
    const float* __restrict__ x, const float* __restrict__ g,
    const float* __restrict__ b, f16* __restrict__ out)
{
    const int row = blockIdx.x;
    const int t = threadIdx.x;
    const float4 xv = ((const float4*)(x + (size_t)row * 1024))[t];
    float s  = xv.x + xv.y + xv.z + xv.w;
    float ss = xv.x * xv.x + xv.y * xv.y + xv.z * xv.z + xv.w * xv.w;
    for (int o = 32; o > 0; o >>= 1) {
        s  += __shfl_down(s, o, 64);
        ss += __shfl_down(ss, o, 64);
    }
    __shared__ float red[8];
    const int wv = t >> 6;
    if ((t & 63) == 0) { red[wv] = s; red[wv + 4] = ss; }
    __syncthreads();
    s  = red[0] + red[1] + red[2] + red[3];
    ss = red[4] + red[5] + red[6] + red[7];
    const float mean = s * (1.f / 1024.f);
    const float var  = ss * (1.f / 1024.f) - mean * mean;
    const float rstd = rsqrtf(var + 1e-5f);
    const float4 gv = ((const float4*)g)[t];
    const float4 bv = ((const float4*)b)[t];
    alignas(8) f16 h[4];
    h[0] = (f16)((xv.x - mean) * rstd * gv.x + bv.x);
    h[1] = (f16)((xv.y - mean) * rstd * gv.y + bv.y);
    h[2] = (f16)((xv.z - mean) * rstd * gv.z + bv.z);
    h[3] = (f16)((xv.w - mean) * rstd * gv.w + bv.w);
    ((uint2*)(out + (size_t)row * 1024))[t] = *(uint2*)h;
}

// f32 -> f16 cast, 4 elems/thread
__global__ __launch_bounds__(256) void cast_f32_f16(
    const float* __restrict__ in, f16* __restrict__ out, int n4)
{
    const int i = blockIdx.x * 256 + threadIdx.x;
    if (i < n4) {
        const float4 v = ((const float4*)in)[i];
        alignas(8) f16 h[4] = {(f16)v.x, (f16)v.y, (f16)v.z, (f16)v.w};
        ((uint2*)out)[i] = *(uint2*)h;
    }
}

// vT[z=(b*16+h)][d][m] = p[b*1024+m][2048 + h*64 + d]   (64x64 LDS tile)
__global__ __launch_bounds__(256) void transpose_v(
    const f16* __restrict__ p, f16* __restrict__ vT)
{
    const int z = blockIdx.y;
    const int b = z >> 4, h = z & 15;
    const int m0 = blockIdx.x * 64;
    __shared__ f16 tile[64][72];
    const int t = threadIdx.x;
    const f16* src = p + (size_t)(b * 1024 + m0) * 4096 + 2048 + h * 64;
#pragma unroll
    for (int pass = 0; pass < 4; ++pass) {
        const int r = (t >> 4) + pass * 16;   // m
        const int c = (t & 15) * 4;           // d
        *(uint2*)&tile[r][c] = *(const uint2*)(src + (size_t)r * 4096 + c);
    }
    __syncthreads();
    f16* dst = vT + (size_t)z * 65536 + m0;
#pragma unroll
    for (int pass = 0; pass < 4; ++pass) {
        const int d  = (t >> 4) + pass * 16;
        const int mc = (t & 15) * 4;
        alignas(8) f16 tmp[4] = {tile[mc][d], tile[mc + 1][d], tile[mc + 2][d], tile[mc + 3][d]};
        *(uint2*)(dst + (size_t)d * 1024 + mc) = *(uint2*)tmp;
    }
}

extern "C" void kernel_launch(void* const* d_in, const int* in_sizes, int n_in,
                              void* d_out, int out_size, void* d_ws, size_t ws_size,
                              hipStream_t stream) {
    const float* x      = (const float*)d_in[0];
    const float* decay  = (const float*)d_in[1];
    const float* ln1_g  = (const float*)d_in[2];
    const float* ln1_b  = (const float*)d_in[3];
    const float* proj_W = (const float*)d_in[4];
    const float* proj_b = (const float*)d_in[5];
    const float* reto_W = (const float*)d_in[6];
    const float* reto_b = (const float*)d_in[7];
    const float* ln2_g  = (const float*)d_in[8];
    const float* ln2_b  = (const float*)d_in[9];
    const float* ffn1_W = (const float*)d_in[10];
    const float* ffn1_b = (const float*)d_in[11];
    const float* ffn2_W = (const float*)d_in[12];
    const float* ffn2_b = (const float*)d_in[13];
    float* out = (float*)d_out;

    // Workspace (114 MB, liveness-aliased):
    //   Wp 8MB [cast..G1] -> gated [attn..G4]
    //   Wr 2MB, W1 8MB, W2 8MB
    //   buf8 8MB: lnx[LN1..G1] -> vT[transp..attn] -> hln[LN2..G5]
    //   p 32MB [G1..attn(xo)] -> ffh [G5..G6]
    //   S 32MB: G4/G6 splitK partials (2x16MB)
    //   y 16MB [G4red..G6]
    char* w = (char*)d_ws;
    auto alloc = [&](size_t bytes) { char* r = w; w += (bytes + 255) & ~(size_t)255; return r; };
    f16*   Wp   = (f16*)alloc((size_t)4096 * 1024 * 2);
    f16*   Wr   = (f16*)alloc((size_t)1024 * 1024 * 2);
    f16*   W1   = (f16*)alloc((size_t)4096 * 1024 * 2);
    f16*   W2   = (f16*)alloc((size_t)1024 * 4096 * 2);
    f16*   buf8 = (f16*)alloc((size_t)4096 * 1024 * 2);
    f16*   p    = (f16*)alloc((size_t)4096 * 4096 * 2);
    f16*   S    = (f16*)alloc((size_t)16 * 1024 * 1024 * 2);
    float* y    = (float*)alloc((size_t)4096 * 1024 * 4);

    f16*   lnx   = buf8;
    f16*   vT    = buf8;
    f16*   hln   = buf8;
    f16*   gated = Wp;
    f16*   ffh   = p;
    float* Pk    = (float*)S;   // split-K partials for G4/G6 (2 x 16MB)

    // weight casts
    cast_f32_f16<<<4096, 256, 0, stream>>>(proj_W, Wp, 1048576);
    cast_f32_f16<<<1024, 256, 0, stream>>>(reto_W, Wr, 262144);
    cast_f32_f16<<<4096, 256, 0, stream>>>(ffn1_W, W1, 1048576);
    cast_f32_f16<<<4096, 256, 0, stream>>>(ffn2_W, W2, 1048576);

    // LN1
    ln_to_f16<<<4096, 256, 0, stream>>>(x, ln1_g, ln1_b, lnx);

    // G1: p = lnx @ proj_W^T + proj_b     [4096,4096] K=1024
    gemm_bt<128, 128, 4, 4, EP_BIAS_F16, 0><<<dim3(32, 32, 1), 256, 0, stream>>>(
        lnx, Wp, p, 4096, 4096, 1024, 1024, 1024, 4096,
        0, 0, 0, 0, 0, 0, 1, 1, 1024, 0, proj_b, nullptr, 0, 0, 0);

    // v transpose (overwrites lnx, dead after G1)
    transpose_v<<<dim3(16, 64), 256, 0, stream>>>(p, vT);

    // fused attention (64 Q-rows x 2 batches, counted-vmcnt pipeline):
    // gated = (QK^T * decay) V * silu(xo)
    attn_fused<<<dim3(16, 32), 256, 0, stream>>>(p, vT, decay, gated);

    // G4: Pk = gated @ reto_W^T  (splitK=2, Kc=512, 128x128, XCD-swizzled)
    gemm_bt<128, 128, 4, 4, EP_PARTIAL_F32, 1><<<dim3(8, 32, 2), 256, 0, stream>>>(
        gated, Wr, Pk, 4096, 1024, 1024, 1024, 1024, 1024,
        0, 0, 0, 0, 0, 0, 1, 2, 512, 4194304, nullptr, nullptr, 0, 0, 0);
    reduce2_bias_res<<<4096, 256, 0, stream>>>(
        (const float4*)Pk, reto_b, (const float4*)x, (float4*)y);

    // LN2
    ln_to_f16<<<4096, 256, 0, stream>>>(y, ln2_g, ln2_b, hln);

    // G5: ffh = gelu(hln @ ffn1_W^T + ffn1_b)   [4096,4096] K=1024
    gemm_bt<128, 128, 4, 4, EP_BIAS_GELU_F16, 0><<<dim3(32, 32, 1), 256, 0, stream>>>(
        hln, W1, ffh, 4096, 4096, 1024, 1024, 1024, 4096,
        0, 0, 0, 0, 0, 0, 1, 1, 1024, 0, ffn1_b, nullptr, 0, 0, 0);

    // G6: Pk = ffh @ ffn2_W^T (splitK=2, Kc=2048, 128x128, XCD-swizzled)
    gemm_bt<128, 128, 4, 4, EP_PARTIAL_F32, 1><<<dim3(8, 32, 2), 256, 0, stream>>>(
        ffh, W2, Pk, 4096, 1024, 4096, 4096, 4096, 1024,
        0, 0, 0, 0, 0, 0, 1, 2, 2048, 4194304, nullptr, nullptr, 0, 0, 0);
    reduce2_bias_res<<<4096, 256, 0, stream>>>(
        (const float4*)Pk, ffn2_b, (const float4*)y, (float4*)out);
}

// Round 6
// 390.819 us; speedup vs baseline: 1.0128x; 1.0128x over previous
//
#include <hip/hip_runtime.h>

// ---------------------------------------------------------------------------
// RetnetBlock fp16-MFMA implementation.
// R12: layout retile for DRAM efficiency — R6..R11 attn invariant at ~55us,
//      ~2.1 TB/s: every stream is short-chunk strided (decay 256B/4KB row,
//      K 128B/8KB, vT 128B/2KB) -> ~30% DRAM efficiency. Fix what we own:
//      (1) p stored slab-tiled p_t[c64][4096][64] (G1 epilogue PTILED flag)
//          -> attn Q/K/XO slabs and K-tiles are 8KB contiguous;
//      (2) vT tile-major vT_t[z][mt][64][64] (transpose_v rewritten)
//          -> attn V-tiles 8KB contiguous;
//      (3) attn: ADDRESSES ONLY changed; R11 counted-vmcnt pipeline kept.
//      (4) G1/G5 gain XCD y-swizzle (XSWZ=1). Decay untouched this round.
// ---------------------------------------------------------------------------

typedef _Float16 f16;
typedef _Float16 f16x8 __attribute__((ext_vector_type(8)));
typedef float floatx4 __attribute__((ext_vector_type(4)));

#define EP_BIAS_F16      0
#define EP_DECAY_F16     1
#define EP_BIAS_GELU_F16 2
#define EP_PARTIAL_F32   3

template <bool F32> struct out_sel { typedef f16 T; };
template <> struct out_sel<true>   { typedef float T; };

__device__ __forceinline__ void gload_lds16(const void* g, void* s) {
    __builtin_amdgcn_global_load_lds(
        (const __attribute__((address_space(1))) unsigned int*)g,
        (__attribute__((address_space(3))) unsigned int*)s, 16, 0, 0);
}

// erf via Abramowitz-Stegun 7.1.26, |abs err| <= 1.5e-7
__device__ __forceinline__ float erf_fast(float x) {
    const float ax = fabsf(x);
    const float t  = __builtin_amdgcn_rcpf(1.f + 0.3275911f * ax);
    const float p  = t * (0.254829592f + t * (-0.284496736f + t * (1.421413741f +
                     t * (-1.453152027f + t * 1.061405429f))));
    const float r  = 1.f - p * __expf(-ax * ax);
    return copysignf(r, x);
}

// ---------------------------------------------------------------------------
// Fused attention: block = 64 Q-rows x one h x TWO batches; 256 thr = 4
// waves, wave w owns Q rows [w*16, w*16+16) x all 64 kv of the tile.
// p is slab-tiled p_t[c64][4096][64]: slab h = Q, 16+h = K, 32+h = V(src),
// 48+h = XO. vT is tile-major vT_t[z][mt][64 d][64 m] (8KB contig tiles).
// 32 steps of (tile 0..15) x (batch 0,1); step s consumes buf[s&3], staged
// at step s-2. Per step: DLOAD(next decay) | sched_barrier | STAGE(s+2) |
// STEP(s) | s_waitcnt vmcnt(4) + s_barrier. (R11 pipeline, new addresses.)
// ---------------------------------------------------------------------------
__global__ __launch_bounds__(256, 2) void attn_fused(
    const f16* __restrict__ p, const f16* __restrict__ vT,
    const float* __restrict__ decay, f16* __restrict__ gated)
{
    const int y  = blockIdx.y;          // bp*16 + h
    const int bp = y >> 4, h = y & 15;
    const int m0 = blockIdx.x * 64;

    __shared__ __align__(16) f16 Kb[4][64 * 64];   // 32 KB, swizzled
    __shared__ __align__(16) f16 Vb[4][64 * 64];   // 32 KB, swizzled
    __shared__ __align__(16) f16 Ss[4][16 * 68];   // 8.7 KB, per-wave, padded

    const int t    = threadIdx.x;
    const int lane = t & 63;
    const int w    = t >> 6;            // 0..3
    const int quad = lane >> 4;
    const int fr   = lane & 15;
    const int wq0  = w * 16;            // wave's Q-row base within block

    const int b0 = bp * 2, b1 = b0 + 1;
    const int z0 = b0 * 16 + h, z1 = z0 + 16;
    // slab-tiled p_t: offset(c64,row,col) = (c64*4096 + row)*64 + col
    const f16*   Qg0 = p + ((size_t)h * 4096 + b0 * 1024 + m0) * 64;
    const f16*   Qg1 = p + ((size_t)h * 4096 + b1 * 1024 + m0) * 64;
    const f16*   Kg0 = p + ((size_t)(16 + h) * 4096 + b0 * 1024) * 64;
    const f16*   Kg1 = p + ((size_t)(16 + h) * 4096 + b1 * 1024) * 64;
    const f16*   Vg0 = vT + (size_t)z0 * 65536;    // [16 mt][64 d][64 m]
    const f16*   Vg1 = vT + (size_t)z1 * 65536;
    const f16*   XOg0 = p + ((size_t)(48 + h) * 4096 + b0 * 1024 + m0) * 64;
    const f16*   XOg1 = p + ((size_t)(48 + h) * 4096 + b1 * 1024 + m0) * 64;
    const float* Dg  = decay + (size_t)h * 1048576 + (size_t)m0 * 1024;

    // Q fragments straight to registers: row wq0+fr, k-chunk kc*4+quad.
    f16x8 q00, q01, q10, q11;
    {
        const size_t qrow = (size_t)(wq0 + fr) * 64;
        q00 = *(const f16x8*)(Qg0 + qrow + (0 * 4 + quad) * 8);
        q01 = *(const f16x8*)(Qg0 + qrow + (1 * 4 + quad) * 8);
        q10 = *(const f16x8*)(Qg1 + qrow + (0 * 4 + quad) * 8);
        q11 = *(const f16x8*)(Qg1 + qrow + (1 * 4 + quad) * 8);
    }

    floatx4 oa0[4] = {}, oa1[4] = {};   // O accumulators, d-tiles tn=0..3
    float dA[16], dB[16];               // decay ping-pong (static indexing)

    // thread's decay base: row (m0+wq0+quad*4), col fr
    const float* Dt = Dg + (size_t)(wq0 + quad * 4) * 1024 + fr;

#define DLOAD(dst, jj) { _Pragma("unroll") \
    for (int tn = 0; tn < 4; ++tn) { _Pragma("unroll") \
      for (int r = 0; r < 4; ++r) \
        dst[tn * 4 + r] = Dt[(size_t)r * 1024 + (jj) + tn * 16]; } \
    __builtin_amdgcn_sched_barrier(0); }

// stage one (batch, tile) pair of K,V into buffer pb; 4 gload_lds/thread.
// Both K-tile and V-tile are 8KB contiguous: base + jj*64 + r*64 + c.
// XOR-swizzled: LDS chunk (r, sc) holds global chunk (r, sc^(r&7)).
#define STAGE(Kgp, Vgp, jj, pb) { _Pragma("unroll") \
    for (int i_ = 0; i_ < 2; ++i_) { \
      const int ci = t + i_ * 256; \
      const int r_ = ci >> 3; \
      const int c_ = ((ci & 7) ^ (r_ & 7)) * 8; \
      gload_lds16((Kgp) + (size_t)(jj) * 64 + r_ * 64 + c_, &Kb[pb][ci * 8]); \
      gload_lds16((Vgp) + (size_t)(jj) * 64 + r_ * 64 + c_, &Vb[pb][ci * 8]); \
    } }

// counted-vmcnt barrier: stage(s+2)'s 4 loads may stay in flight.
#define VMBAR(N) { asm volatile("s_waitcnt vmcnt(" #N ")" ::: "memory"); \
    __builtin_amdgcn_s_barrier(); __builtin_amdgcn_sched_barrier(0); }

// one step: S = Q K^T (8 MFMA) -> xdecay -> wave-private Ss -> O += S V (8 MFMA)
#define STEP(qa, qb, oa, dreg, pb) { \
    floatx4 sa[4] = {}; \
    _Pragma("unroll") \
    for (int kc = 0; kc < 2; ++kc) { \
      const int cc = kc * 4 + quad; \
      f16x8 bf[4]; \
      _Pragma("unroll") \
      for (int tn = 0; tn < 4; ++tn) { \
        const int kv = tn * 16 + fr; \
        bf[tn] = *(const f16x8*)&Kb[pb][(kv * 8 + (cc ^ (kv & 7))) * 8]; \
      } \
      _Pragma("unroll") \
      for (int tn = 0; tn < 4; ++tn) \
        sa[tn] = __builtin_amdgcn_mfma_f32_16x16x32_f16(kc ? (qb) : (qa), bf[tn], sa[tn], 0, 0, 0); \
    } \
    _Pragma("unroll") \
    for (int tn = 0; tn < 4; ++tn) { _Pragma("unroll") \
      for (int r = 0; r < 4; ++r) \
        Ss[w][(quad * 4 + r) * 68 + tn * 16 + fr] = (f16)(sa[tn][r] * dreg[tn * 4 + r]); } \
    _Pragma("unroll") \
    for (int kc = 0; kc < 2; ++kc) { \
      const int cc = kc * 4 + quad; \
      const f16x8 af = *(const f16x8*)&Ss[w][fr * 68 + cc * 8]; \
      f16x8 bf[4]; \
      _Pragma("unroll") \
      for (int tn = 0; tn < 4; ++tn) { \
        const int d = tn * 16 + fr; \
        bf[tn] = *(const f16x8*)&Vb[pb][(d * 8 + (cc ^ (d & 7))) * 8]; \
      } \
      _Pragma("unroll") \
      for (int tn = 0; tn < 4; ++tn) \
        oa[tn] = __builtin_amdgcn_mfma_f32_16x16x32_f16(af, bf[tn], oa[tn], 0, 0, 0); \
    } }

// epilogue: gate with silu(xo), stage via wave-private Ss, coalesced flush
#define EPILOG(oa, XOgp, bq) { \
    _Pragma("unroll") \
    for (int tn = 0; tn < 4; ++tn) { _Pragma("unroll") \
      for (int r = 0; r < 4; ++r) { \
        const int qrow = wq0 + quad * 4 + r; \
        const int d = tn * 16 + fr; \
        float g = (float)XOgp[(size_t)qrow * 64 + d]; \
        g = g * __builtin_amdgcn_rcpf(1.f + __expf(-g)); \
        Ss[w][(quad * 4 + r) * 68 + tn * 16 + fr] = (f16)(oa[tn][r] * g); \
      } } \
    f16* Og = gated + (size_t)((bq) * 1024 + m0 + wq0) * 1024 + h * 64; \
    _Pragma("unroll") \
    for (int i = 0; i < 2; ++i) { \
      const int jj = lane + i * 64; \
      const int rr = jj >> 3; \
      const int cc = jj & 7; \
      const uint2 lo = *(const uint2*)&Ss[w][rr * 68 + cc * 8]; \
      const uint2 hi = *(const uint2*)&Ss[w][rr * 68 + cc * 8 + 4]; \
      uint4 val = make_uint4(lo.x, lo.y, hi.x, hi.y); \
      *(uint4*)(Og + (size_t)rr * 1024 + cc * 8) = val; \
    } }

    // prologue: DLOAD(dA) first (must drain here), then stages for steps 0,1.
    // vmcnt(4) leaves exactly stage(1)'s 4 ops in flight; drains Q, dA, stage(0).
    DLOAD(dA, 0);
    STAGE(Kg0, Vg0, 0, 0);              // step0 (t0,b0) -> buf0
    STAGE(Kg1, Vg1, 0, 1);              // step1 (t0,b1) -> buf1
    VMBAR(4);

    for (int i = 0; i < 7; ++i) {
        const int j1 = i * 128 + 64;    // tile 2i+1 base
        const int j2 = i * 128 + 128;   // tile 2i+2 base
        // s=4i: consume buf0 (t2i,b0,dA) | dload dB(t2i+1) | stage s+2 -> buf2
        DLOAD(dB, j1);
        STAGE(Kg0, Vg0, j1, 2);
        STEP(q00, q01, oa0, dA, 0);
        VMBAR(4);
        // s=4i+1: consume buf1 (t2i,b1,dA) | stage s+2 -> buf3
        STAGE(Kg1, Vg1, j1, 3);
        STEP(q10, q11, oa1, dA, 1);
        VMBAR(4);
        // s=4i+2: consume buf2 (t2i+1,b0,dB) | dload dA(t2i+2) | stage -> buf0
        DLOAD(dA, j2);
        STAGE(Kg0, Vg0, j2, 0);
        STEP(q00, q01, oa0, dB, 2);
        VMBAR(4);
        // s=4i+3: consume buf3 (t2i+1,b1,dB) | stage s+2 -> buf1
        STAGE(Kg1, Vg1, j2, 1);
        STEP(q10, q11, oa1, dB, 3);
        VMBAR(4);
    }
    // tail: steps 28..31 (tile 14 via dA from buf0/1, tile 15 via dB buf2/3)
    {
        // step 28: consume buf0 (t14,b0,dA) | dload dB(t15) | stage 30 -> buf2
        DLOAD(dB, 960);
        STAGE(Kg0, Vg0, 960, 2);
        STEP(q00, q01, oa0, dA, 0);
        VMBAR(4);
        // step 29: consume buf1 (t14,b1,dA) | stage 31 -> buf3
        STAGE(Kg1, Vg1, 960, 3);
        STEP(q10, q11, oa1, dA, 1);
        VMBAR(4);
        // step 30: consume buf2 (t15,b0,dB); nothing staged after -> vmcnt(0)
        STEP(q00, q01, oa0, dB, 2);
        VMBAR(0);
        // step 31: consume buf3 (t15,b1,dB); no barrier needed after
        STEP(q10, q11, oa1, dB, 3);
    }

    EPILOG(oa0, XOg0, b0);
    EPILOG(oa1, XOg1, b1);

#undef DLOAD
#undef STAGE
#undef VMBAR
#undef STEP
#undef EPILOG
}

// C[m,n] = sum_k A[m,k] * B[n,k]  ("BT" form). 256 thr = 4 waves, 2x2 grid.
// blockIdx.z packs ((zo*inner + zi)*nsplit + ks); split ks covers K-range
// [ks*Kc,(ks+1)*Kc), partial written at cOff + ks*sCk (EP_PARTIAL_F32,
// direct f32 stores, no LDS staging).
// XSWZ: XCD y-chunk swizzle — requires (gridDim.x*gridDim.y) % 8 == 0.
// PTILED: f16 output written slab-tiled [gcol>>6][4096 rows][64] instead of
// row-major (for attn-friendly contiguous slabs). cOff ignored when PTILED.
// K (and Kc) must be multiples of 64.
template <int BM, int BN, int WM, int WN, int EP, int XSWZ, int PTILED = 0>
__global__ __launch_bounds__(256, 4) void gemm_bt(
    const f16* __restrict__ A, const f16* __restrict__ B, void* __restrict__ Cv,
    int M, int N, int K, int lda, int ldb, int ldc,
    long long sAo, long long sAi, long long sBo, long long sBi,
    long long sCo, long long sCi, int inner,
    int nsplit, int Kc, long long sCk,
    const float* __restrict__ bias,
    const void* __restrict__ aux, long long sXo, long long sXi, int ldaux)
{
    constexpr bool OUT_F32 = (EP == EP_PARTIAL_F32);
    typedef typename out_sel<OUT_F32>::T OutT;
    constexpr int ESIZE       = OUT_F32 ? 4 : 2;
    constexpr int CSTRIDE     = BN + 4;                  // stage row stride, elems
    constexpr int TILE_BYTES  = (BM + BN) * 64 * 2;      // BK=64 f16 tiles
    constexpr int STAGE_BYTES = OUT_F32 ? 0 : BM * CSTRIDE * ESIZE;
    constexpr int SMEM_BYTES  = TILE_BYTES > STAGE_BYTES ? TILE_BYTES : STAGE_BYTES;

    __shared__ __align__(16) char smem[SMEM_BYTES];
    f16*  As = (f16*)smem;
    f16*  Bs = (f16*)(smem + BM * 128);
    OutT* Cs = (OutT*)smem;

    int z = blockIdx.z;
    const int ks = z % nsplit; z /= nsplit;
    const int zo = z / inner, zi = z % inner;
    A += zo * sAo + zi * sAi;
    B += zo * sBo + zi * sBi;
    const long long cOff = (long long)zo * sCo + (long long)zi * sCi + (long long)ks * sCk;
    const long long xOff = (long long)zo * sXo + (long long)zi * sXi;

    int bx = blockIdx.x, by = blockIdx.y;
    if constexpr (XSWZ) {
        // hw XCD = (bx + gx*by + gx*gy*bz) % 8; with gx % 8 == 0 this is bx%8.
        // Remap so XCD c covers a contiguous band of y-slabs for all x.
        const int gx  = gridDim.x;
        const int nb  = gx * gridDim.y;          // must be % 8 == 0
        const int lin = bx + gx * by;
        const int nlin = (lin & 7) * (nb >> 3) + (lin >> 3);
        bx = nlin % gx;
        by = nlin / gx;
    }
    const int m0 = by * BM;
    const int n0 = bx * BN;

    const int t    = threadIdx.x;
    const int lane = t & 63;
    const int w    = t >> 6;
    const int wm   = (w >> 1) * (WM * 16);
    const int wn   = (w & 1) * (WN * 16);
    const int fr   = lane & 15;          // A/B row within 16-tile
    const int quad = lane >> 4;          // 0..3, k-offset quad*8

    constexpr int ACH = BM / 32;         // 16B chunks per thread for A tile
    constexpr int BCH = BN / 32;

    floatx4 acc[WM][WN] = {};

    const int kbeg = ks * Kc, kend = kbeg + Kc;
    for (int kk = kbeg; kk < kend; kk += 64) {
        // async global->LDS, 16B/lane. LDS layout XOR-swizzled: LDS chunk
        // (r, sc) holds global chunk (r, sc ^ (r&7)).
#pragma unroll
        for (int i = 0; i < ACH; ++i) {
            const int ci = t + i * 256;
            const int r  = ci >> 3;
            const int c  = ((ci & 7) ^ (r & 7)) * 8;
            gload_lds16(A + (size_t)(m0 + r) * lda + kk + c, &As[ci * 8]);
        }
#pragma unroll
        for (int i = 0; i < BCH; ++i) {
            const int ci = t + i * 256;
            const int r  = ci >> 3;
            const int c  = ((ci & 7) ^ (r & 7)) * 8;
            gload_lds16(B + (size_t)(n0 + r) * ldb + kk + c, &Bs[ci * 8]);
        }
        __syncthreads();

#pragma unroll
        for (int kh = 0; kh < 2; ++kh) {
            const int cc = kh * 4 + quad;             // 16B chunk within row
            f16x8 af[WM], bf[WN];
#pragma unroll
            for (int tm = 0; tm < WM; ++tm) {
                const int r = wm + tm * 16 + fr;
                af[tm] = *(const f16x8*)&As[(r * 8 + (cc ^ (r & 7))) * 8];
            }
#pragma unroll
            for (int tn = 0; tn < WN; ++tn) {
                const int r = wn + tn * 16 + fr;
                bf[tn] = *(const f16x8*)&Bs[(r * 8 + (cc ^ (r & 7))) * 8];
            }
#pragma unroll
            for (int tm = 0; tm < WM; ++tm)
#pragma unroll
                for (int tn = 0; tn < WN; ++tn)
                    acc[tm][tn] = __builtin_amdgcn_mfma_f32_16x16x32_f16(af[tm], bf[tn], acc[tm][tn], 0, 0, 0);
        }
        __syncthreads();
    }

    // ---- epilogue: C/D layout col=lane&15, row=(lane>>4)*4+reg [m89] ----
    const int er = quad * 4;
    const int ec = lane & 15;
    if constexpr (OUT_F32) {
        // direct f32 stores: per instr, wave writes 4 x 64B aligned segments
        float* Pg = (float*)Cv + cOff;
#pragma unroll
        for (int tm = 0; tm < WM; ++tm)
#pragma unroll
            for (int tn = 0; tn < WN; ++tn)
#pragma unroll
                for (int r = 0; r < 4; ++r) {
                    const int grow = m0 + wm + tm * 16 + er + r;
                    const int gcol = n0 + wn + tn * 16 + ec;
                    Pg[(size_t)grow * ldc + gcol] = acc[tm][tn][r];
                }
        return;
    }

#pragma unroll
    for (int tm = 0; tm < WM; ++tm) {
#pragma unroll
        for (int tn = 0; tn < WN; ++tn) {
#pragma unroll
            for (int r = 0; r < 4; ++r) {
                const int lrow = wm + tm * 16 + er + r;       // 0..BM-1
                const int col  = wn + tn * 16 + ec;           // 0..BN-1
                const int grow = m0 + lrow;
                const int gcol = n0 + col;
                const float v = acc[tm][tn][r];
                float val;
                if constexpr (EP == EP_BIAS_F16) {
                    val = v + bias[gcol];
                } else if constexpr (EP == EP_DECAY_F16) {
                    const float* dk = (const float*)aux + xOff;
                    val = v * dk[(size_t)grow * ldaux + gcol];
                } else if constexpr (EP == EP_BIAS_GELU_F16) {
                    const float u = v + bias[gcol];
                    val = 0.5f * u * (1.f + erf_fast(u * 0.70710678118f));
                } else {
                    val = v;
                }
                Cs[lrow * CSTRIDE + col] = (OutT)val;
            }
        }
    }
    __syncthreads();

    constexpr int PER_ROW = BN * ESIZE / 16;          // 16B chunks per row
    constexpr int NCHUNK  = (BM * PER_ROW) / 256;     // chunks per thread
#pragma unroll
    for (int i = 0; i < NCHUNK; ++i) {
        const int j  = t + i * 256;
        const int rr = j / PER_ROW;
        const int cc = j - rr * PER_ROW;
        const char* src = smem + (size_t)rr * (CSTRIDE * ESIZE) + (size_t)cc * 16;
        const uint2 lo = *(const uint2*)src;          // stride 264B: 8B-aligned
        const uint2 hi = *(const uint2*)(src + 8);
        uint4 val = make_uint4(lo.x, lo.y, hi.x, hi.y);
        char* dst;
        if constexpr (PTILED) {
            // slab-tiled: [gcol>>6][row][gcol&63], 16B chunk spans 8 cols
            const int gc0 = n0 + cc * 8;
            dst = (char*)Cv +
                (((size_t)(gc0 >> 6) * 4096 + (m0 + rr)) * 64 + (gc0 & 63)) * 2;
        } else {
            dst = (char*)Cv +
                (size_t)(cOff + (long long)(m0 + rr) * ldc + n0) * ESIZE +
                (size_t)cc * 16;
        }
        *(uint4*)dst = val;
    }
}

// out[4096,1024] = P0 + P1 + bias[col] + res   (all f32, float4 vectorized)
__global__ __launch_bounds__(256) void reduce2_bias_res(
    const float4* __restrict__ P, const float* __restrict__ bias,
    const float4* __restrict__ res, float4* __restrict__ out)
{
    const int i = blockIdx.x * 256 + threadIdx.x;   // 1,048,576 groups
    const int col4 = i & 255;
    const float4 a = P[i];
    const float4 b = P[i + 1048576];
    const float4 r = res[i];
    const float4 bi = ((const float4*)bias)[col4];
    float4 o;
    o.x = a.x + b.x + r.x + bi.x;
    o.y = a.y + b.y + r.y + bi.y;
    o.z = a.z + b.z + r.z + bi.z;
    o.w = a.w + b.w + r.w + bi.w;
    out[i] = o;
}

// LayerNorm over D=1024, one block (256 thr) per row, fp16 output.
__global__ __launch_bounds__(256) void ln_to_f16(
    const float* __restrict__ x, const float* __restrict__ g,
    const float* __restrict__ b, f16* __restrict__ out)
{
    const int row = blockIdx.x;
    const int t = threadIdx.x;
    const float4 xv = ((const float4*)(x + (size_t)row * 1024))[t];
    float s  = xv.x + xv.y + xv.z + xv.w;
    float ss = xv.x * xv.x + xv.y * xv.y + xv.z * xv.z + xv.w * xv.w;
    for (int o = 32; o > 0; o >>= 1) {
        s  += __shfl_down(s, o, 64);
        ss += __shfl_down(ss, o, 64);
    }
    __shared__ float red[8];
    const int wv = t >> 6;
    if ((t & 63) == 0) { red[wv] = s; red[wv + 4] = ss; }
    __syncthreads();
    s  = red[0] + red[1] + red[2] + red[3];
    ss = red[4] + red[5] + red[6] + red[7];
    const float mean = s * (1.f / 1024.f);
    const float var  = ss * (1.f / 1024.f) - mean * mean;
    const float rstd = rsqrtf(var + 1e-5f);
    const float4 gv = ((const float4*)g)[t];
    const float4 bv = ((const float4*)b)[t];
    alignas(8) f16 h[4];
    h[0] = (f16)((xv.x - mean) * rstd * gv.x + bv.x);
    h[1] = (f16)((xv.y - mean) * rstd * gv.y + bv.y);
    h[2] = (f16)((xv.z - mean) * rstd * gv.z + bv.z);
    h[3] = (f16)((xv.w - mean) * rstd * gv.w + bv.w);
    ((uint2*)(out + (size_t)row * 1024))[t] = *(uint2*)h;
}

// f32 -> f16 cast, 4 elems/thread
__global__ __launch_bounds__(256) void cast_f32_f16(
    const float* __restrict__ in, f16* __restrict__ out, int n4)
{
    const int i = blockIdx.x * 256 + threadIdx.x;
    if (i < n4) {
        const float4 v = ((const float4*)in)[i];
        alignas(8) f16 h[4] = {(f16)v.x, (f16)v.y, (f16)v.z, (f16)v.w};
        ((uint2*)out)[i] = *(uint2*)h;
    }
}

// vT_t[z][mt=m0>>6][d][m] from p_t slab 32+h (both sides 8KB-contiguous tiles)
__global__ __launch_bounds__(256) void transpose_v(
    const f16* __restrict__ p, f16* __restrict__ vT)
{
    const int z = blockIdx.y;
    const int b = z >> 4, h = z & 15;
    const int m0 = blockIdx.x * 64;
    __shared__ f16 tile[64][72];
    const int t = threadIdx.x;
    const f16* src = p + ((size_t)(32 + h) * 4096 + b * 1024 + m0) * 64;
#pragma unroll
    for (int pass = 0; pass < 4; ++pass) {
        const int r = (t >> 4) + pass * 16;   // m within tile
        const int c = (t & 15) * 4;           // d
        *(uint2*)&tile[r][c] = *(const uint2*)(src + (size_t)r * 64 + c);
    }
    __syncthreads();
    f16* dst = vT + (size_t)z * 65536 + (size_t)(m0 >> 6) * 4096;
#pragma unroll
    for (int pass = 0; pass < 4; ++pass) {
        const int d  = (t >> 4) + pass * 16;
        const int mc = (t & 15) * 4;
        alignas(8) f16 tmp[4] = {tile[mc][d], tile[mc + 1][d], tile[mc + 2][d], tile[mc + 3][d]};
        *(uint2*)(dst + (size_t)d * 64 + mc) = *(uint2*)tmp;
    }
}

extern "C" void kernel_launch(void* const* d_in, const int* in_sizes, int n_in,
                              void* d_out, int out_size, void* d_ws, size_t ws_size,
                              hipStream_t stream) {
    const float* x      = (const float*)d_in[0];
    const float* decay  = (const float*)d_in[1];
    const float* ln1_g  = (const float*)d_in[2];
    const float* ln1_b  = (const float*)d_in[3];
    const float* proj_W = (const float*)d_in[4];
    const float* proj_b = (const float*)d_in[5];
    const float* reto_W = (const float*)d_in[6];
    const float* reto_b = (const float*)d_in[7];
    const float* ln2_g  = (const float*)d_in[8];
    const float* ln2_b  = (const float*)d_in[9];
    const float* ffn1_W = (const float*)d_in[10];
    const float* ffn1_b = (const float*)d_in[11];
    const float* ffn2_W = (const float*)d_in[12];
    const float* ffn2_b = (const float*)d_in[13];
    float* out = (float*)d_out;

    // Workspace (114 MB, liveness-aliased):
    //   Wp 8MB [cast..G1] -> gated [attn..G4]
    //   Wr 2MB, W1 8MB, W2 8MB
    //   buf8 8MB: lnx[LN1..G1] -> vT[transp..attn] -> hln[LN2..G5]
    //   p 32MB [G1..attn(xo)] (slab-tiled p_t) -> ffh [G5..G6]
    //   S 32MB: G4/G6 splitK partials (2x16MB)
    //   y 16MB [G4red..G6]
    char* w = (char*)d_ws;
    auto alloc = [&](size_t bytes) { char* r = w; w += (bytes + 255) & ~(size_t)255; return r; };
    f16*   Wp   = (f16*)alloc((size_t)4096 * 1024 * 2);
    f16*   Wr   = (f16*)alloc((size_t)1024 * 1024 * 2);
    f16*   W1   = (f16*)alloc((size_t)4096 * 1024 * 2);
    f16*   W2   = (f16*)alloc((size_t)1024 * 4096 * 2);
    f16*   buf8 = (f16*)alloc((size_t)4096 * 1024 * 2);
    f16*   p    = (f16*)alloc((size_t)4096 * 4096 * 2);
    f16*   S    = (f16*)alloc((size_t)16 * 1024 * 1024 * 2);
    float* y    = (float*)alloc((size_t)4096 * 1024 * 4);

    f16*   lnx   = buf8;
    f16*   vT    = buf8;
    f16*   hln   = buf8;
    f16*   gated = Wp;
    f16*   ffh   = p;
    float* Pk    = (float*)S;   // split-K partials for G4/G6 (2 x 16MB)

    // weight casts
    cast_f32_f16<<<4096, 256, 0, stream>>>(proj_W, Wp, 1048576);
    cast_f32_f16<<<1024, 256, 0, stream>>>(reto_W, Wr, 262144);
    cast_f32_f16<<<4096, 256, 0, stream>>>(ffn1_W, W1, 1048576);
    cast_f32_f16<<<4096, 256, 0, stream>>>(ffn2_W, W2, 1048576);

    // LN1
    ln_to_f16<<<4096, 256, 0, stream>>>(x, ln1_g, ln1_b, lnx);

    // G1: p_t = lnx @ proj_W^T + proj_b   [4096,4096] K=1024, slab-tiled out
    gemm_bt<128, 128, 4, 4, EP_BIAS_F16, 1, 1><<<dim3(32, 32, 1), 256, 0, stream>>>(
        lnx, Wp, p, 4096, 4096, 1024, 1024, 1024, 4096,
        0, 0, 0, 0, 0, 0, 1, 1, 1024, 0, proj_b, nullptr, 0, 0, 0);

    // v transpose (overwrites lnx, dead after G1): p_t slab 32+h -> vT_t tiles
    transpose_v<<<dim3(16, 64), 256, 0, stream>>>(p, vT);

    // fused attention (64 Q-rows x 2 batches, counted-vmcnt pipeline,
    // contiguous K/V/Q/XO tiles): gated = (QK^T * decay) V * silu(xo)
    attn_fused<<<dim3(16, 32), 256, 0, stream>>>(p, vT, decay, gated);

    // G4: Pk = gated @ reto_W^T  (splitK=2, Kc=512, 128x128, XCD-swizzled)
    gemm_bt<128, 128, 4, 4, EP_PARTIAL_F32, 1><<<dim3(8, 32, 2), 256, 0, stream>>>(
        gated, Wr, Pk, 4096, 1024, 1024, 1024, 1024, 1024,
        0, 0, 0, 0, 0, 0, 1, 2, 512, 4194304, nullptr, nullptr, 0, 0, 0);
    reduce2_bias_res<<<4096, 256, 0, stream>>>(
        (const float4*)Pk, reto_b, (const float4*)x, (float4*)y);

    // LN2
    ln_to_f16<<<4096, 256, 0, stream>>>(y, ln2_g, ln2_b, hln);

    // G5: ffh = gelu(hln @ ffn1_W^T + ffn1_b)   [4096,4096] K=1024
    gemm_bt<128, 128, 4, 4, EP_BIAS_GELU_F16, 1><<<dim3(32, 32, 1), 256, 0, stream>>>(
        hln, W1, ffh, 4096, 4096, 1024, 1024, 1024, 4096,
        0, 0, 0, 0, 0, 0, 1, 1, 1024, 0, ffn1_b, nullptr, 0, 0, 0);

    // G6: Pk = ffh @ ffn2_W^T (splitK=2, Kc=2048, 128x128, XCD-swizzled)
    gemm_bt<128, 128, 4, 4, EP_PARTIAL_F32, 1><<<dim3(8, 32, 2), 256, 0, stream>>>(
        ffh, W2, Pk, 4096, 1024, 4096, 4096, 4096, 1024,
        0, 0, 0, 0, 0, 0, 1, 2, 2048, 4194304, nullptr, nullptr, 0, 0, 0);
    reduce2_bias_res<<<4096, 256, 0, stream>>>(
        (const float4*)Pk, ffn2_b, (const float4*)y, (float4*)out);
}